// Round 8
// baseline (385.425 us; speedup 1.0000x reference)
//
#include <hip/hip_runtime.h>
#include <hip/hip_bf16.h>

#define LR 0.01f
#define WD 0.01f
#define SCALE_G 1048576.0f      // 2^20: lift G out of f16-subnormal range
#define INV_SCALE_G 9.5367431640625e-07f  // 2^-20

// GEMM geometry: BM=256, BN=128, BK=64, 512 threads = 8 waves (2M x 4N),
// per-wave output 128x32 = acc[8][2] frags of 16x16.
#define BUFU 24576              // u16 per staging buffer: A 256x64 + B 128x64
#define TRT 264                 // transposed-image stride (256+8)
#define RMS 136                 // row-major-image stride (128+8)

typedef short s16x8 __attribute__((ext_vector_type(8)));
typedef _Float16 f16x8 __attribute__((ext_vector_type(8)));
typedef float f32x4 __attribute__((ext_vector_type(4)));
typedef unsigned short u16;

__device__ __forceinline__ u16 f2h(float f) {
    _Float16 h = (_Float16)f;
    return *reinterpret_cast<u16*>(&h);
}
__device__ __forceinline__ float h2f(u16 u) {
    _Float16 h;
    *reinterpret_cast<u16*>(&h) = u;
    return (float)h;
}
__device__ __forceinline__ float tanh_fast(float x) {
    float t = fminf(fmaxf(2.f * x, -30.f), 30.f);
    float e = __expf(t);
    return 1.f - 2.f * __builtin_amdgcn_rcpf(e + 1.f);
}

// ---------------------------------------------------------------------------
// Staging with XOR swizzle on the GLOBAL source (rule #21): rows are 128B =
// 8 chunks of 16B; chunk chl = chp ^ (row&7). A: 2048 slots (4 issues/thread),
// B: 1024 slots (2 issues/thread). gload_lds dest is linear.
// ---------------------------------------------------------------------------
__device__ __forceinline__ void stage_A(const u16* gA, int ldg, u16* lds, int q) {
    int s = threadIdx.x + q * 512;            // 0..2047
    int row = s >> 3, chp = s & 7;
    int chl = chp ^ (row & 7);
    __builtin_amdgcn_global_load_lds(
        (const __attribute__((address_space(1))) void*)(gA + (size_t)row * ldg + chl * 8),
        (__attribute__((address_space(3))) void*)(lds + s * 8), 16, 0, 0);
}
__device__ __forceinline__ void stage_B(const u16* gB, int ldg, u16* lds, int q) {
    int s = threadIdx.x + q * 512;            // 0..1023
    int row = s >> 3, chp = s & 7;
    int chl = chp ^ (row & 7);
    __builtin_amdgcn_global_load_lds(
        (const __attribute__((address_space(1))) void*)(gB + (size_t)row * ldg + chl * 8),
        (__attribute__((address_space(3))) void*)(lds + 16384 + s * 8), 16, 0, 0);
}

// swizzled fragment reads; chunk = ks*4 + hi (hi = lane>>4), row-XOR'd
__device__ __forceinline__ f16x8 fragA(const u16* P, int r, int ks, int hi) {
    return *(const f16x8*)(P + r * 64 + ((((ks << 2) | hi)) ^ (r & 7)) * 8);
}
__device__ __forceinline__ f16x8 fragB(const u16* P, int r, int ks, int hi) {
    return *(const f16x8*)(P + 16384 + r * 64 + ((((ks << 2) | hi)) ^ (r & 7)) * 8);
}

#define MEMFENCE asm volatile("" ::: "memory")

// ---------------------------------------------------------------------------
// Deep-phase MFMA GEMM: C[M,N] = A[M,K] @ Bt[N,K]^T, f16 in, fp32 accum.
// 256x128 tile, BK=64, 8 waves, 3-buffer staging, counted vmcnt(6) once per
// K-tile (tile t+1 stays in flight while t+2 issues), 4 phases per K-tile:
// {ds_read subtile ; 2 staging issues ; barrier ; setprio(1) ; 8 MFMA ;
//  setprio(0) ; [phase3: vmcnt gate] ; barrier}.
// EPI: 0 tanh->Tf(rm)+TT(tr) ; 1 h_t(fp32)+G'(rm)+GT'(tr)+gb2 ;
//      2 dtanh->dAT(tr)+gb1 ; 3 atomicAdd fp32 (split-K weight grads)
// ---------------------------------------------------------------------------
template <int EPI>
__global__ __launch_bounds__(512) void k_mfma(
    const u16* __restrict__ A, const u16* __restrict__ Bt,
    int nbx, int Md, int Nd, int Kd, int Kslice,
    const float* __restrict__ bias, const float* __restrict__ xtgt,
    const u16* __restrict__ Th,
    float* __restrict__ outf, u16* __restrict__ outb, u16* __restrict__ outbT,
    float* __restrict__ gbias, float scale) {
    __shared__ u16 smem[3 * BUFU];       // 147456 B staging; reused for epilogue
    __shared__ float colacc[128];

    // XCD-aware swizzle (all grids have gridDim.x % 8 == 0)
    const int nwg = gridDim.x;
    const int sw = (blockIdx.x & 7) * (nwg >> 3) + (blockIdx.x >> 3);
    const int m0 = (sw / nbx) * 256, n0 = (sw % nbx) * 128;
    const int kb = blockIdx.y * Kslice;

    const int lane = threadIdx.x & 63, wid = threadIdx.x >> 6;
    const int wrow = (wid >> 2) * 128;   // 2 M-wave-rows
    const int wcol = (wid & 3) * 32;     // 4 N-wave-cols
    const int lm = lane & 15;
    const int hi = lane >> 4;

    f32x4 acc[8][2] = {};

    const u16* gA = A + (size_t)m0 * Kd + kb;
    const u16* gB = Bt + (size_t)n0 * Kd + kb;
    const int nt = Kslice >> 6;          // K-tiles of 64 (>= 8 for all shapes)

    if (EPI == 1 || EPI == 2)
        if (threadIdx.x < 128) colacc[threadIdx.x] = 0.f;

    // prologue: stage tiles 0,1 (12 outstanding per wave)
    for (int q = 0; q < 4; ++q) stage_A(gA, Kd, smem, q);
    for (int q = 0; q < 2; ++q) stage_B(gB, Kd, smem, q);
    for (int q = 0; q < 4; ++q) stage_A(gA + 64, Kd, smem + BUFU, q);
    for (int q = 0; q < 2; ++q) stage_B(gB + 64, Kd, smem + BUFU, q);
    asm volatile("s_waitcnt vmcnt(6)" ::: "memory");  // tile0's 6 done
    MEMFENCE; __builtin_amdgcn_s_barrier(); MEMFENCE;

    for (int t = 0; t < nt; ++t) {
        u16* P = smem + (t % 3) * BUFU;
        u16* Pn = smem + ((t + 2) % 3) * BUFU;
        const u16* gA2 = gA + (size_t)(t + 2) * 64;
        const u16* gB2 = gB + (size_t)(t + 2) * 64;
        const bool st = (t + 2) < nt;
        f16x8 bfr[2][2];
#pragma unroll
        for (int p = 0; p < 4; ++p) {
            f16x8 afr[2][2];
#pragma unroll
            for (int mm = 0; mm < 2; ++mm)
#pragma unroll
                for (int ks = 0; ks < 2; ++ks)
                    afr[mm][ks] = fragA(P, wrow + (2 * p + mm) * 16 + lm, ks, hi);
            if (p == 0) {
#pragma unroll
                for (int j = 0; j < 2; ++j)
#pragma unroll
                    for (int ks = 0; ks < 2; ++ks)
                        bfr[j][ks] = fragB(P, wcol + j * 16 + lm, ks, hi);
            }
            if (st) {
                if (p == 0) { stage_A(gA2, Kd, Pn, 0); stage_A(gA2, Kd, Pn, 1); }
                else if (p == 1) { stage_A(gA2, Kd, Pn, 2); stage_A(gA2, Kd, Pn, 3); }
                else if (p == 2) { stage_B(gB2, Kd, Pn, 0); stage_B(gB2, Kd, Pn, 1); }
            }
            MEMFENCE; __builtin_amdgcn_s_barrier(); MEMFENCE;
            __builtin_amdgcn_s_setprio(1);
#pragma unroll
            for (int mm = 0; mm < 2; ++mm)
#pragma unroll
                for (int j = 0; j < 2; ++j)
#pragma unroll
                    for (int ks = 0; ks < 2; ++ks)
                        acc[2 * p + mm][j] = __builtin_amdgcn_mfma_f32_16x16x32_f16(
                            afr[mm][ks], bfr[j][ks], acc[2 * p + mm][j], 0, 0, 0);
            __builtin_amdgcn_s_setprio(0);
            if (p == 3) {   // counted gate: tile t+1 must be ready for next iter
                if (t + 2 < nt)      asm volatile("s_waitcnt vmcnt(6)" ::: "memory");
                else if (t + 1 < nt) asm volatile("s_waitcnt vmcnt(0)" ::: "memory");
            }
            MEMFENCE; __builtin_amdgcn_s_barrier(); MEMFENCE;
        }
    }

    // C/D layout (m89): col = lane&15, row = (lane>>4)*4 + reg
    const int rbase = hi * 4;

    if (EPI == 3) {
#pragma unroll
        for (int i = 0; i < 8; ++i) {
            const int row0 = m0 + wrow + i * 16 + rbase;
#pragma unroll
            for (int j = 0; j < 2; ++j) {
                const int col = n0 + wcol + j * 16 + lm;
#pragma unroll
                for (int r = 0; r < 4; ++r)
                    atomicAdd(&outf[(size_t)(row0 + r) * Nd + col], acc[i][j][r]);
            }
        }
        return;
    }

    // ---- compute f16 payload + direct fp32 outputs + colsums ----
    ushort4 hv[8][2];
#pragma unroll
    for (int i = 0; i < 8; ++i) {
        const int row0 = m0 + wrow + i * 16 + rbase;
#pragma unroll
        for (int j = 0; j < 2; ++j) {
            const int col = n0 + wcol + j * 16 + lm;
            if (EPI == 0) {
                float bcol = bias[col];
                hv[i][j].x = f2h(tanh_fast(acc[i][j][0] + bcol));
                hv[i][j].y = f2h(tanh_fast(acc[i][j][1] + bcol));
                hv[i][j].z = f2h(tanh_fast(acc[i][j][2] + bcol));
                hv[i][j].w = f2h(tanh_fast(acc[i][j][3] + bcol));
            } else if (EPI == 1) {
                float csum = 0.f, bcol = bias[col];
#pragma unroll
                for (int r = 0; r < 4; ++r) {
                    size_t idx = (size_t)(row0 + r) * Nd + col;
                    float pv = acc[i][j][r] + bcol;
                    outf[idx] = pv;
                    float gf = scale * (pv - xtgt[idx]);
                    csum += gf;
                    ((u16*)&hv[i][j])[r] = f2h(gf);
                }
                atomicAdd(&colacc[wcol + j * 16 + lm], csum);
            } else {  // EPI == 2
                float csum = 0.f;
#pragma unroll
                for (int r = 0; r < 4; ++r) {
                    size_t idx = (size_t)(row0 + r) * Nd + col;
                    float tv = h2f(Th[idx]);
                    float da = acc[i][j][r] * (1.0f - tv * tv);
                    csum += da;
                    ((u16*)&hv[i][j])[r] = f2h(da);
                }
                atomicAdd(&colacc[wcol + j * 16 + lm], csum);
            }
        }
    }

    // ---- pass A: transposed output via LDS [col][row] image (stride TRT) ----
    __syncthreads();
#pragma unroll
    for (int i = 0; i < 8; ++i)
#pragma unroll
        for (int j = 0; j < 2; ++j)
            *(ushort4*)(smem + (wcol + j * 16 + lm) * TRT + wrow + i * 16 + rbase) =
                hv[i][j];
    __syncthreads();
#pragma unroll
    for (int p = 0; p < 8; ++p) {
        int cid = threadIdx.x + p * 512;
        int trr = cid >> 5, ch = cid & 31;     // 128 rows x 32 chunks
        s16x8 v = *(const s16x8*)(smem + trr * TRT + ch * 8);
        *(s16x8*)(outbT + (size_t)(n0 + trr) * Md + m0 + ch * 8) = v;
    }

    // ---- pass B: row-major f16 output via LDS [row][col] image ----
    if (EPI <= 1) {
        __syncthreads();
#pragma unroll
        for (int i = 0; i < 8; ++i)
#pragma unroll
            for (int j = 0; j < 2; ++j)
#pragma unroll
                for (int r = 0; r < 4; ++r)
                    smem[(wrow + i * 16 + rbase + r) * RMS + wcol + j * 16 + lm] =
                        ((u16*)&hv[i][j])[r];
        __syncthreads();
#pragma unroll
        for (int p = 0; p < 8; ++p) {
            int cid = threadIdx.x + p * 512;
            int rr = cid >> 4, ch = cid & 15;  // 256 rows x 16 chunks
            s16x8 v = *(const s16x8*)(smem + rr * RMS + ch * 8);
            *(s16x8*)(outb + (size_t)(m0 + rr) * Nd + n0 + ch * 8) = v;
        }
    }

    if (EPI == 1 || EPI == 2) {
        __syncthreads();
        if (threadIdx.x < 128)
            atomicAdd(&gbias[n0 + threadIdx.x], colacc[threadIdx.x]);
    }
}

// ---------------------------------------------------------------------------
// fp32 [R,C] -> optional f16 row-major + optional f16 transposed
// ---------------------------------------------------------------------------
__global__ void k_prep(const float* __restrict__ in, u16* __restrict__ rm,
                       u16* __restrict__ tr, int R, int C) {
    __shared__ float tile[64][65];
    const int tx = threadIdx.x & 63, ty = threadIdx.x >> 6;
    const int c0 = blockIdx.x * 64, r0 = blockIdx.y * 64;
#pragma unroll
    for (int i = 0; i < 64; i += 4) {
        size_t idx = (size_t)(r0 + ty + i) * C + c0 + tx;
        float v = in[idx];
        tile[ty + i][tx] = v;
        if (rm) rm[idx] = f2h(v);
    }
    __syncthreads();
    if (tr) {
#pragma unroll
        for (int i = 0; i < 64; i += 4)
            tr[(size_t)(c0 + ty + i) * R + r0 + tx] = f2h(tile[tx][ty + i]);
    }
}

// merged learned-optimizer update (grads contiguous gw1|gb1|gw2|gb2)
__global__ void k_update_all(
    const float* __restrict__ w1, const float* __restrict__ b1,
    const float* __restrict__ w2, const float* __restrict__ b2,
    const float* __restrict__ g, float* __restrict__ out,
    int n1, int n2, int n3, int n4,
    const float* __restrict__ Wm1, const float* __restrict__ bm1,
    const float* __restrict__ Wm2, const float* __restrict__ bm2,
    int M, float invScale) {
    __shared__ float s1[64], s2[64], s3[64];
    if (threadIdx.x < M) {
        s1[threadIdx.x] = Wm1[threadIdx.x];
        s2[threadIdx.x] = bm1[threadIdx.x];
        s3[threadIdx.x] = Wm2[threadIdx.x];
    }
    __syncthreads();
    int i = blockIdx.x * blockDim.x + threadIdx.x;
    int n = n1 + n2 + n3 + n4;
    if (i >= n) return;
    const float* p;
    int off;
    if (i < n1) { p = w1; off = 0; }
    else if (i < n1 + n2) { p = b1; off = n1; }
    else if (i < n1 + n2 + n3) { p = w2; off = n1 + n2; }
    else { p = b2; off = n1 + n2 + n3; }
    float gv = g[i] * invScale;
    float u = bm2[0];
#pragma unroll 8
    for (int m = 0; m < M; ++m) u += tanh_fast(fmaf(gv, s1[m], s2[m])) * s3[m];
    float pv = p[i - off];
    out[i] = pv - (LR * u + WD * pv);
}

__global__ void k_zero(float* __restrict__ p, int n) {
    int i = blockIdx.x * blockDim.x + threadIdx.x;
    if (i < n) p[i] = 0.f;
}

extern "C" void kernel_launch(void* const* d_in, const int* in_sizes, int n_in,
                              void* d_out, int out_size, void* d_ws, size_t ws_size,
                              hipStream_t stream) {
    const float* x_t      = (const float*)d_in[0];
    const float* x_target = (const float*)d_in[1];
    const float* w1  = (const float*)d_in[2];
    const float* b1  = (const float*)d_in[3];
    const float* w2  = (const float*)d_in[4];
    const float* b2  = (const float*)d_in[5];
    const float* Wm1 = (const float*)d_in[6];
    const float* bm1 = (const float*)d_in[7];
    const float* Wm2 = (const float*)d_in[8];
    const float* bm2 = (const float*)d_in[9];

    const int H = in_sizes[3];      // 1024
    const int D = in_sizes[5];      // 512
    const int N = in_sizes[0] / D;  // 16384
    const int M = in_sizes[6];      // 32

    // ---- workspace: grads FIRST, contiguous in OUTPUT order ----
    char* w = (char*)d_ws;
    float* gw1 = (float*)w;            w += (size_t)D * H * 4;  // [D,H]
    float* gb1 = (float*)w;            w += (size_t)H * 4;
    float* gw2 = (float*)w;            w += (size_t)H * D * 4;  // [H,D]
    float* gb2 = (float*)w;            w += (size_t)D * 4;
    u16* Tf   = (u16*)w;               w += (size_t)N * H * 2;  // T f16 rm
    u16* TT   = (u16*)w;               w += (size_t)N * H * 2;  // T^T [H,N]
    u16* dAT  = (u16*)w;               w += (size_t)N * H * 2;  // dA^T [H,N]
    u16* Gb   = (u16*)w;               w += (size_t)N * D * 2;  // G' rm
    u16* GT   = (u16*)w;               w += (size_t)N * D * 2;  // G'^T [D,N]
    u16* xf   = (u16*)w;               w += (size_t)N * D * 2;  // x f16 rm
    u16* xT   = (u16*)w;               w += (size_t)N * D * 2;  // x^T [D,N]
    u16* w1T  = (u16*)w;               w += (size_t)D * H * 2;  // w1^T [H,D]
    u16* w2T  = (u16*)w;               w += (size_t)D * H * 2;  // w2^T [D,H]
    u16* w2b  = (u16*)w;               w += (size_t)H * D * 2;  // w2 rm [H,D]

    float* out  = (float*)d_out;
    float* h_t  = out;                    // [N,D]
    float* o_w1 = h_t + (size_t)N * D;    // [D,H] (updates contiguous from here)

    dim3 blk(256), blkG(512);
    const float scaleG = (2.0f / ((float)N * (float)D)) * SCALE_G;

    // zero atomic accumulators (gw1,gb1,gw2,gb2 contiguous)
    int zn = D * H + H + H * D + D;
    k_zero<<<dim3((zn + 255) / 256), blk, 0, stream>>>(gw1, zn);

    // input prep: x -> xf + xT ; w1 -> w1T ; w2 -> w2b + w2T
    k_prep<<<dim3(D / 64, N / 64), blk, 0, stream>>>(x_t, xf, xT, N, D);
    k_prep<<<dim3(H / 64, D / 64), blk, 0, stream>>>(w1, nullptr, w1T, D, H);
    k_prep<<<dim3(D / 64, H / 64), blk, 0, stream>>>(w2, w2b, w2T, H, D);

    // fwd1: T = tanh(x@w1 + b1) -> Tf + TT   [N,H], K=D
    k_mfma<0><<<dim3((N / 256) * (H / 128), 1), blkG, 0, stream>>>(
        xf, w1T, H / 128, N, H, D, D, b1, nullptr, nullptr,
        nullptr, Tf, TT, nullptr, 0.f);

    // fwd2: h = T@w2 + b2 (fp32) ; G' -> Gb + GT + gb2   [N,D], K=H
    k_mfma<1><<<dim3((N / 256) * (D / 128), 1), blkG, 0, stream>>>(
        Tf, w2T, D / 128, N, D, H, H, b2, x_target, nullptr,
        h_t, Gb, GT, gb2, scaleG);

    // dA' = (G' @ w2^T) * (1 - T^2) -> dAT + gb1   [N,H], K=D
    k_mfma<2><<<dim3((N / 256) * (H / 128), 1), blkG, 0, stream>>>(
        Gb, w2b, H / 128, N, H, D, D, nullptr, nullptr, Tf,
        nullptr, nullptr, dAT, gb1, 0.f);

    // gw2' = T^T @ G'  [H,D]: A=TT[H,N], Bt=GT[D,N], split-K=16
    const int SPLIT = 16;
    k_mfma<3><<<dim3((H / 256) * (D / 128), SPLIT), blkG, 0, stream>>>(
        TT, GT, D / 128, H, D, N, N / SPLIT, nullptr, nullptr, nullptr,
        gw2, nullptr, nullptr, nullptr, 0.f);

    // gw1' = x^T @ dA'  [D,H]: A=xT[D,N], Bt=dAT[H,N]
    k_mfma<3><<<dim3((D / 256) * (H / 128), SPLIT), blkG, 0, stream>>>(
        xT, dAT, H / 128, D, H, N, N / SPLIT, nullptr, nullptr, nullptr,
        gw1, nullptr, nullptr, nullptr, 0.f);

    // merged learned-optimizer update
    int nAll = D * H + H + H * D + D;
    k_update_all<<<dim3((nAll + 255) / 256), blk, 0, stream>>>(
        w1, b1, w2, b2, gw1, o_w1, D * H, H, H * D, D,
        Wm1, bm1, Wm2, bm2, M, INV_SCALE_G);
}